// Round 7
// baseline (96.895 us; speedup 1.0000x reference)
//
#include <hip/hip_runtime.h>
#include <math.h>

// pred: (1,16,384,384) fp32, labels int32 same shape, area fp32[256]
constexpr int ZN = 16, YN = 384, XN = 384;
constexpr int NZ = 17, NY = 385, NX = 385;   // node grid
constexpr int NP = NY * NX;                  // 148225 nodes per z-slab
constexpr int NROWS = NZ * NY;               // 6545 node rows -> one block each
constexpr int TPB = 384;                     // 6 waves; thread t = voxel column x=t

__device__ __forceinline__ float sigm(float p) {
    return __fdividef(1.f, 1.f + __expf(-p));
}

__global__ __launch_bounds__(TPB) void sd_main(
        const float* __restrict__ pred,
        const int*   __restrict__ labels,
        const float* __restrict__ area,
        float*       __restrict__ partial)   // [num NROWS][den NROWS][vol NROWS]
{
    // Re-indexed LUT: idx = (own_col_label_nibble << 4) | prev_col_label_nibble,
    // nibble bit r = 2dz+dy; original corner k = dz*4+dy*2+dx (dx: 0=prev, 1=own)
    __shared__ float s_area[256];
    // column state entries: entry[x+1] = col x, entry[0] = x=-1 padding (zeros)
    // layout: 6 dwords/entry: s0 s1 s2 s3 q bits
    __shared__ float s_col[385 * 6];
    __shared__ float rn[6], rd[6], rv[6];

    const int t = threadIdx.x;
    if (t < 256) {
        const int own = t >> 4, prv = t & 15;
        int code = 0;
#pragma unroll
        for (int r = 0; r < 4; ++r)
            code |= (((prv >> r) & 1) << (2 * r)) | (((own >> r) & 1) << (2 * r + 1));
        s_area[t] = area[code];
    }

    const int row = blockIdx.x;
    const int z = row / NY;                  // 0..16
    const int y = row - z * NY;              // 0..384

    // ---- Phase 1: own voxel column state (x = t), block-uniform predication ----
    float s[4] = {0.f, 0.f, 0.f, 0.f};
    float q = 0.f;
    int bits = 0;                            // label nibble | predbit nibble << 4
    {
        const bool vz0 = (z >= 1), vz1 = (z <= ZN - 1);
        const bool vy0 = (y >= 1), vy1 = (y <= YN - 1);
        const bool val[4] = { vz0 && vy0, vz0 && vy1, vz1 && vy0, vz1 && vy1 };
        const int  off[4] = {
            ((z - 1) * YN + (y - 1)) * XN + t,
            ((z - 1) * YN + y)       * XN + t,
            (z * YN + (y - 1))       * XN + t,
            (z * YN + y)             * XN + t };
#pragma unroll
        for (int r = 0; r < 4; ++r) {
            if (val[r]) {
                const float p = pred[off[r]];
                const int   l = labels[off[r]];
                const float sv = sigm(p);    // sigmoid once per voxel (per block)
                s[r] = sv;
                const float d = sv - (float)l;
                q = fmaf(d, d, q);
                bits |= (l << r) | ((int)(p > 0.f) << (r + 4));
            }
        }
    }
    {
        float* e = &s_col[(t + 1) * 6];
        if (t == 383) e = &s_col[0];         // nobody reads entry 384+1; t383 fills pad entry 0
        // t=383's own entry isn't read by anyone (node 384 handled in-register);
        // so t383 writes the zero pad entry instead. All others write entry t+1.
        if (t == 383) {
            e[0] = 0.f; e[1] = 0.f; e[2] = 0.f; e[3] = 0.f; e[4] = 0.f;
            ((int*)e)[5] = 0;
        } else {
            e[0] = s[0]; e[1] = s[1]; e[2] = s[2]; e[3] = s[3]; e[4] = q;
            ((int*)e)[5] = bits;
        }
    }
    __syncthreads();

    // ---- Phase 2: node x = t (prev col from LDS, own col in registers) ----
    float num = 0.f, den = 0.f, vol = 0.f;
    auto node = [&](const float* sp, float qp, int bp,
                    const float* so, float qo, int bo) {
        const int idxL = ((bo & 15) << 4) | (bp & 15);
        const int idxP = ((bo >> 4) << 4) | (bp >> 4);
        const float la = s_area[idxL];
        const float pa = s_area[idxP];
        num = fmaf(2.f * la, 1.f - (qp + qo) * 0.125f, num);
        den += la + pa;
        if (idxL == 0 || idxL == 255) {      // interior: all 8 labels uniform
            const bool one = (idxL == 255);
            float b = 0.f;
#pragma unroll
            for (int r = 0; r < 4; ++r) {
                b += __logf(fmaxf(one ? sp[r] : 1.f - sp[r], 1e-12f))
                   + __logf(fmaxf(one ? so[r] : 1.f - so[r], 1e-12f));
            }
            vol -= b;
        }
    };
    {
        const float* e = &s_col[t * 6];      // prev column (x = t-1; t=0 -> zero pad)
        float ps[4] = { e[0], e[1], e[2], e[3] };
        const float pq = e[4];
        const int   pb = ((const int*)e)[5];
        node(ps, pq, pb, s, q, bits);
        if (t == 383) {                      // node x=384: prev = own col, own = padding
            const float zs[4] = {0.f, 0.f, 0.f, 0.f};
            node(s, q, bits, zs, 0.f, 0);
        }
    }

    // ---- Reduction: wave shuffle + LDS across 6 waves ----
#pragma unroll
    for (int off = 32; off > 0; off >>= 1) {
        num += __shfl_down(num, off);
        den += __shfl_down(den, off);
        vol += __shfl_down(vol, off);
    }
    const int lane = t & 63, w = t >> 6;
    if (lane == 0) { rn[w] = num; rd[w] = den; rv[w] = vol; }
    __syncthreads();
    if (t == 0) {
        float n = 0.f, d = 0.f, v = 0.f;
#pragma unroll
        for (int i = 0; i < 6; ++i) { n += rn[i]; d += rd[i]; v += rv[i]; }
        partial[row]             = n;
        partial[NROWS + row]     = d;
        partial[2 * NROWS + row] = v;
    }
}

__global__ __launch_bounds__(256) void sd_final(
        const float* __restrict__ partial, float* __restrict__ out)
{
    double n = 0.0, d = 0.0, v = 0.0;
    for (int b = threadIdx.x; b < NROWS; b += 256) {
        n += (double)partial[b];
        d += (double)partial[NROWS + b];
        v += (double)partial[2 * NROWS + b];
    }
#pragma unroll
    for (int off = 32; off > 0; off >>= 1) {
        n += __shfl_down(n, off);
        d += __shfl_down(d, off);
        v += __shfl_down(v, off);
    }
    __shared__ double sn[4], sd_[4], sv[4];
    const int lane = threadIdx.x & 63, w = threadIdx.x >> 6;
    if (lane == 0) { sn[w] = n; sd_[w] = d; sv[w] = v; }
    __syncthreads();
    if (threadIdx.x == 0) {
        const double num = sn[0] + sn[1] + sn[2] + sn[3];
        const double den = sd_[0] + sd_[1] + sd_[2] + sd_[3];
        const double vol = (sv[0] + sv[1] + sv[2] + sv[3]) / (8.0 * (double)NP);
        const double dice = 1.0 - (num + 1e-3) / (den + 1e-3);
        out[0] = (float)(dice + vol);
    }
}

extern "C" void kernel_launch(void* const* d_in, const int* in_sizes, int n_in,
                              void* d_out, int out_size, void* d_ws, size_t ws_size,
                              hipStream_t stream)
{
    const float* pred   = (const float*)d_in[0];
    const int*   labels = (const int*)d_in[1];
    const float* area   = (const float*)d_in[2];
    float* out     = (float*)d_out;
    float* partial = (float*)d_ws;   // 3*NROWS floats, fully overwritten each call

    sd_main<<<NROWS, TPB, 0, stream>>>(pred, labels, area, partial);
    sd_final<<<1, 256, 0, stream>>>(partial, out);
}

// Round 8
// 86.574 us; speedup vs baseline: 1.1192x; 1.1192x over previous
//
#include <hip/hip_runtime.h>
#include <math.h>

// pred: (1,16,384,384) fp32, labels int32 same shape, area fp32[256]
constexpr int ZN = 16, YN = 384, XN = 384;
constexpr int NZ = 17, NY = 385, NX = 385;   // node grid
constexpr int NP = NY * NX;                  // 148225 nodes per z-slab
constexpr int NROWS = NZ * NY;               // 6545 node rows
constexpr int NWAVES = NROWS * 2;            // 2 x-chunks per row = 13090 waves
constexpr int TPB = 512;                     // 8 waves/block
constexpr int BLOCKS = (NWAVES + 7) / 8;     // 1637 (same ramp as champion R5)

__device__ __forceinline__ float sigm(float p) {
    return __fdividef(1.f, 1.f + __expf(-p));
}

__global__ __launch_bounds__(TPB, 8) void sd_main(
        const float* __restrict__ pred,
        const int*   __restrict__ labels,
        const float* __restrict__ area,
        float*       __restrict__ partial)   // [num BLOCKS][den BLOCKS][vol BLOCKS]
{
    // Re-indexed LUT: idx = (own_col_nibble << 4) | prev_col_nibble, nibble bit r = 2dz+dy
    __shared__ float s_area[256];
    __shared__ float rn[8], rd[8], rv[8];
    const int t = threadIdx.x;
    if (t < 256) {
        const int own = t >> 4, prv = t & 15;
        int code = 0;
#pragma unroll
        for (int r = 0; r < 4; ++r)
            code |= (((prv >> r) & 1) << (2 * r)) | (((own >> r) & 1) << (2 * r + 1));
        s_area[t] = area[code];
    }
    __syncthreads();

    const int lane = t & 63;
    const int wid  = blockIdx.x * 8 + (t >> 6);

    float num = 0.f, den = 0.f, vol = 0.f;

    if (wid < NWAVES) {
        const int row = wid >> 1;            // node row 0..6544
        const int c   = wid & 1;             // x-chunk (0: cols 0..191, 1: 192..383)
        const int z = row / NY;              // 0..16
        const int y = row - z * NY;          // 0..384

        bool rval[4]; int base[4];
#pragma unroll
        for (int r = 0; r < 4; ++r) {
            const int zz = z - 1 + (r >> 1);
            const int yy = y - 1 + (r & 1);
            rval[r] = ((unsigned)zz < (unsigned)ZN) & ((unsigned)yy < (unsigned)YN);
            base[r] = (zz * YN + yy) * XN;
        }

        // ghost column (x = 192c - 1) for lane 0; c=0 -> zero padding
        float gs[4] = {0.f, 0.f, 0.f, 0.f};
        float gq = 0.f; int gb = 0;
        if (c == 1 && lane == 0) {
#pragma unroll
            for (int r = 0; r < 4; ++r) {
                if (rval[r]) {
                    const float p = pred[base[r] + 191];
                    const int   l = labels[base[r] + 191];
                    const float sv = sigm(p);
                    gs[r] = sv;
                    const float d = sv - (float)l;
                    gq = fmaf(d, d, gq);
                    gb |= (l << r) | ((int)(p > 0.f) << (r + 4));
                }
            }
        }

        // own 3 columns xb..xb+2
        const int xb = c * 192 + 3 * lane;
        float s[3][4];
        float q[3]  = {0.f, 0.f, 0.f};
        int   cb[3] = {0, 0, 0};
#pragma unroll
        for (int r = 0; r < 4; ++r) {
            if (rval[r]) {
                const float* pp = pred + base[r] + xb;
                const int*   lp = labels + base[r] + xb;
                float p[3]; int l[3];
#pragma unroll
                for (int j = 0; j < 3; ++j) { p[j] = pp[j]; l[j] = lp[j]; }
#pragma unroll
                for (int j = 0; j < 3; ++j) {
                    const float sv = sigm(p[j]);
                    s[j][r] = sv;
                    const float d = sv - (float)l[j];
                    q[j] = fmaf(d, d, q[j]);
                    cb[j] |= (l[j] << r) | ((int)(p[j] > 0.f) << (r + 4));
                }
            } else {
#pragma unroll
                for (int j = 0; j < 3; ++j) s[j][r] = 0.f;   // pad after sigmoid -> 0
            }
        }

        auto node = [&](const float* sp, float qp, int bp,
                        const float* so, float qo, int bo) {
            const int idxL = ((bo & 15) << 4) | (bp & 15);
            const int idxP = (bo & 0xF0) | (bp >> 4);
            const float la = s_area[idxL];
            const float pa = s_area[idxP];
            num = fmaf(2.f * la, 1.f - (qp + qo) * 0.125f, num);
            den += la + pa;
            if (idxL == 0 || idxL == 255) {  // interior: all 8 labels uniform
                const bool one = (idxL == 255);
                float b = 0.f;
#pragma unroll
                for (int r = 0; r < 4; ++r) {
                    b += __logf(fmaxf(one ? sp[r] : 1.f - sp[r], 1e-12f))
                       + __logf(fmaxf(one ? so[r] : 1.f - so[r], 1e-12f));
                }
                vol -= b;
            }
        };

        // prev column (x = xb-1) = lane-1's col 2; lane 0 -> ghost
        float ps[4]; float pq; int pb;
#pragma unroll
        for (int r = 0; r < 4; ++r) ps[r] = __shfl_up(s[2][r], 1);
        pq = __shfl_up(q[2], 1);
        pb = __shfl_up(cb[2], 1);
        if (lane == 0) {
#pragma unroll
            for (int r = 0; r < 4; ++r) ps[r] = gs[r];
            pq = gq; pb = gb;
        }

        node(ps,   pq,   pb,    s[0], q[0], cb[0]);
        node(s[0], q[0], cb[0], s[1], q[1], cb[1]);
        node(s[1], q[1], cb[1], s[2], q[2], cb[2]);
        if (c == 1 && lane == 63) {          // node x=384: own col entirely padding
            const float zs[4] = {0.f, 0.f, 0.f, 0.f};
            node(s[2], q[2], cb[2], zs, 0.f, 0);
        }
    }

    // wave + block reduction
#pragma unroll
    for (int off = 32; off > 0; off >>= 1) {
        num += __shfl_down(num, off);
        den += __shfl_down(den, off);
        vol += __shfl_down(vol, off);
    }
    const int w = t >> 6;
    if (lane == 0) { rn[w] = num; rd[w] = den; rv[w] = vol; }
    __syncthreads();
    if (t == 0) {
        float n = 0.f, d = 0.f, v = 0.f;
#pragma unroll
        for (int i = 0; i < 8; ++i) { n += rn[i]; d += rd[i]; v += rv[i]; }
        partial[blockIdx.x]              = n;
        partial[BLOCKS + blockIdx.x]     = d;
        partial[2 * BLOCKS + blockIdx.x] = v;
    }
}

__global__ __launch_bounds__(256) void sd_final(
        const float* __restrict__ partial, float* __restrict__ out)
{
    double n = 0.0, d = 0.0, v = 0.0;
    for (int b = threadIdx.x; b < BLOCKS; b += 256) {
        n += (double)partial[b];
        d += (double)partial[BLOCKS + b];
        v += (double)partial[2 * BLOCKS + b];
    }
#pragma unroll
    for (int off = 32; off > 0; off >>= 1) {
        n += __shfl_down(n, off);
        d += __shfl_down(d, off);
        v += __shfl_down(v, off);
    }
    __shared__ double sn[4], sd_[4], sv[4];
    const int lane = threadIdx.x & 63, w = threadIdx.x >> 6;
    if (lane == 0) { sn[w] = n; sd_[w] = d; sv[w] = v; }
    __syncthreads();
    if (threadIdx.x == 0) {
        const double num = sn[0] + sn[1] + sn[2] + sn[3];
        const double den = sd_[0] + sd_[1] + sd_[2] + sd_[3];
        const double vol = (sv[0] + sv[1] + sv[2] + sv[3]) / (8.0 * (double)NP);
        const double dice = 1.0 - (num + 1e-3) / (den + 1e-3);
        out[0] = (float)(dice + vol);
    }
}

extern "C" void kernel_launch(void* const* d_in, const int* in_sizes, int n_in,
                              void* d_out, int out_size, void* d_ws, size_t ws_size,
                              hipStream_t stream)
{
    const float* pred   = (const float*)d_in[0];
    const int*   labels = (const int*)d_in[1];
    const float* area   = (const float*)d_in[2];
    float* out     = (float*)d_out;
    float* partial = (float*)d_ws;   // 3*BLOCKS floats, fully overwritten each call

    sd_main<<<BLOCKS, TPB, 0, stream>>>(pred, labels, area, partial);
    sd_final<<<1, 256, 0, stream>>>(partial, out);
}

// Round 9
// 84.697 us; speedup vs baseline: 1.1440x; 1.0222x over previous
//
#include <hip/hip_runtime.h>
#include <math.h>

// pred: (1,16,384,384) fp32, labels int32 same shape, area fp32[256]
constexpr int ZN = 16, YN = 384, XN = 384;
constexpr int NZ = 17, NY = 385, NX = 385;   // node grid
constexpr int NP = NY * NX;                  // 148225 nodes per z-slab
constexpr int NROWS = NZ * NY;               // 6545 node rows, one per wave
constexpr int BLOCKS = (NROWS + 3) / 4;      // 1637 blocks x 4 waves

__device__ __forceinline__ float sigm(float p) {
    return __fdividef(1.f, 1.f + __expf(-p));
}

__global__ __launch_bounds__(256) void sd_main(
        const float* __restrict__ pred,
        const int*   __restrict__ labels,
        const float* __restrict__ area,
        float*       __restrict__ partial)   // [num BLOCKS][den BLOCKS][vol BLOCKS]
{
    // Re-indexed LUT: idx = (own_col_nibble << 4) | prev_col_nibble, nibble bit r = 2dz+dy
    // (original corner k = dz*4+dy*2+dx; dx=0 prev col, dx=1 own col)
    __shared__ float s_area[256];
    {
        const int t = threadIdx.x;
        const int own = t >> 4, prv = t & 15;
        int code = 0;
#pragma unroll
        for (int r = 0; r < 4; ++r)
            code |= (((prv >> r) & 1) << (2 * r)) | (((own >> r) & 1) << (2 * r + 1));
        s_area[t] = area[code];
    }
    __syncthreads();

    const int lane = threadIdx.x & 63;
    // wave-uniform row id in SGPR -> scalar bases, saddr-form loads
    const int wid = __builtin_amdgcn_readfirstlane(blockIdx.x * 4 + (threadIdx.x >> 6));

    float num = 0.f, den = 0.f, vol = 0.f;

    if (wid < NROWS) {
        const int z = wid / NY;              // 0..16   (scalar)
        const int y = wid - z * NY;          // 0..384  (scalar)

        bool rval[4]; int base[4];
#pragma unroll
        for (int r = 0; r < 4; ++r) {
            const int zz = z - 1 + (r >> 1);
            const int yy = y - 1 + (r & 1);
            rval[r] = ((unsigned)zz < (unsigned)ZN) & ((unsigned)yy < (unsigned)YN);
            base[r] = (zz * YN + yy) * XN;   // scalar
        }

        auto node = [&](const float* sp, float qp, int bp,
                        const float* so, float qo, int bo) {
            const int idxL = ((bo & 15) << 4) | (bp & 15);
            const int idxP = (bo & 0xF0) | (bp >> 4);
            const float la = s_area[idxL];
            const float pa = s_area[idxP];
            num = fmaf(2.f * la, 1.f - (qp + qo) * 0.125f, num);
            den += la + pa;
            if (idxL == 0 || idxL == 255) {  // interior: all 8 labels uniform (~0.8%)
                const bool one = (idxL == 255);
                float b = 0.f;
#pragma unroll
                for (int r = 0; r < 4; ++r) {
                    b += __logf(fmaxf(one ? sp[r] : 1.f - sp[r], 1e-12f))
                       + __logf(fmaxf(one ? so[r] : 1.f - so[r], 1e-12f));
                }
                vol -= b;
            }
        };

        const int src = (lane + 63) & 63;    // rotate-down-by-1 source lane
        const bool l0 = (lane == 0);

        // rotated state of previous j-segment (j=-1 -> x=-1 zero padding)
        float rp_s[4] = {0.f, 0.f, 0.f, 0.f};
        float rp_q = 0.f; int rp_b = 0;
        // own state of previous j-segment, for the final node x=384 (lane 63)
        float last_s[4]; float last_q = 0.f; int last_b = 0;

#pragma unroll
        for (int j = 0; j < 6; ++j) {
            const int xo = j * 64 + lane;    // own voxel column; coalesced across lanes
            float s[4] = {0.f, 0.f, 0.f, 0.f};
            float q = 0.f; int b = 0;
#pragma unroll
            for (int r = 0; r < 4; ++r) {
                if (rval[r]) {               // wave-uniform branch
                    const float p = pred[base[r] + xo];
                    const int   l = labels[base[r] + xo];
                    const float sv = sigm(p);
                    s[r] = sv;
                    const float d = sv - (float)l;
                    q = fmaf(d, d, q);
                    b |= (l << r) | ((int)(p > 0.f) << (r + 4));
                }
            }
            // prev-col state: rot[lane] = state[(lane-1)&63]; lane0 takes rot of j-1
            float ps[4], pq; int pb;
#pragma unroll
            for (int r = 0; r < 4; ++r) {
                const float ro = __shfl(s[r], src);
                ps[r] = l0 ? rp_s[r] : ro;
                rp_s[r] = ro;
            }
            {
                const float ro = __shfl(q, src);
                pq = l0 ? rp_q : ro;
                rp_q = ro;
            }
            {
                const int ro = __shfl(b, src);
                pb = l0 ? rp_b : ro;
                rp_b = ro;
            }
            node(ps, pq, pb, s, q, b);
            if (j == 5) {
#pragma unroll
                for (int r = 0; r < 4; ++r) last_s[r] = s[r];
                last_q = q; last_b = b;
            }
        }
        if (lane == 63) {                    // node x=384: prev = col 383, own = padding
            const float zs[4] = {0.f, 0.f, 0.f, 0.f};
            node(last_s, last_q, last_b, zs, 0.f, 0);
        }
    }

    // wave + block reduction
#pragma unroll
    for (int off = 32; off > 0; off >>= 1) {
        num += __shfl_down(num, off);
        den += __shfl_down(den, off);
        vol += __shfl_down(vol, off);
    }
    __shared__ float rn[4], rd[4], rv[4];
    const int w = threadIdx.x >> 6;
    if (lane == 0) { rn[w] = num; rd[w] = den; rv[w] = vol; }
    __syncthreads();
    if (threadIdx.x == 0) {
        partial[blockIdx.x]              = rn[0] + rn[1] + rn[2] + rn[3];
        partial[BLOCKS + blockIdx.x]     = rd[0] + rd[1] + rd[2] + rd[3];
        partial[2 * BLOCKS + blockIdx.x] = rv[0] + rv[1] + rv[2] + rv[3];
    }
}

__global__ __launch_bounds__(256) void sd_final(
        const float* __restrict__ partial, float* __restrict__ out)
{
    double n = 0.0, d = 0.0, v = 0.0;
    for (int b = threadIdx.x; b < BLOCKS; b += 256) {
        n += (double)partial[b];
        d += (double)partial[BLOCKS + b];
        v += (double)partial[2 * BLOCKS + b];
    }
#pragma unroll
    for (int off = 32; off > 0; off >>= 1) {
        n += __shfl_down(n, off);
        d += __shfl_down(d, off);
        v += __shfl_down(v, off);
    }
    __shared__ double sn[4], sd_[4], sv[4];
    const int lane = threadIdx.x & 63, w = threadIdx.x >> 6;
    if (lane == 0) { sn[w] = n; sd_[w] = d; sv[w] = v; }
    __syncthreads();
    if (threadIdx.x == 0) {
        const double num = sn[0] + sn[1] + sn[2] + sn[3];
        const double den = sd_[0] + sd_[1] + sd_[2] + sd_[3];
        const double vol = (sv[0] + sv[1] + sv[2] + sv[3]) / (8.0 * (double)NP);
        const double dice = 1.0 - (num + 1e-3) / (den + 1e-3);
        out[0] = (float)(dice + vol);
    }
}

extern "C" void kernel_launch(void* const* d_in, const int* in_sizes, int n_in,
                              void* d_out, int out_size, void* d_ws, size_t ws_size,
                              hipStream_t stream)
{
    const float* pred   = (const float*)d_in[0];
    const int*   labels = (const int*)d_in[1];
    const float* area   = (const float*)d_in[2];
    float* out     = (float*)d_out;
    float* partial = (float*)d_ws;   // 3*BLOCKS floats, fully overwritten each call

    sd_main<<<BLOCKS, 256, 0, stream>>>(pred, labels, area, partial);
    sd_final<<<1, 256, 0, stream>>>(partial, out);
}